// Round 4
// baseline (115.629 us; speedup 1.0000x reference)
//
#include <hip/hip_runtime.h>
#include <math.h>

#define S_LEN 2048
#define DMODEL 1024
#define NHEAD 16
#define DHEAD 64
#define WIN 128
#define NQKV 1152

typedef _Float16 f16x8 __attribute__((ext_vector_type(8)));
typedef float f32x4 __attribute__((ext_vector_type(4)));

__device__ __forceinline__ ushort f2h(float f) {
  union { _Float16 h; ushort u; } v; v.h = (_Float16)f; return v.u;
}

typedef __attribute__((address_space(1))) const unsigned GU;
typedef __attribute__((address_space(3))) unsigned LU;
__device__ __forceinline__ void async16(const ushort* g, ushort* l) {
  __builtin_amdgcn_global_load_lds((GU*)g, (LU*)l, 16, 0, 0);
}

// ---------------------------------------------------------------- convert fp32 -> f16
__global__ __launch_bounds__(256)
void convert_kernel(const float4* __restrict__ x, const float4* __restrict__ wq,
                    const float4* __restrict__ wo,
                    ushort4* __restrict__ x16, ushort4* __restrict__ w16,
                    ushort4* __restrict__ wo16) {
  const int NX4 = (S_LEN * DMODEL) / 4;       // 524288
  const int NW4 = (NQKV * DMODEL) / 4;        // 294912
  const int NO4 = (DMODEL * DMODEL) / 4;      // 262144
  const int i = blockIdx.x * 256 + threadIdx.x;
  if (i < NX4) {
    const float4 v = x[i];
    ushort4 h; h.x = f2h(v.x); h.y = f2h(v.y); h.z = f2h(v.z); h.w = f2h(v.w);
    x16[i] = h;
  } else if (i < NX4 + NW4) {
    const int j = i - NX4;
    const float s = ((j >> 8) >= 2 * DHEAD) ? 8.0f : 1.0f;  // fold sqrt(D) into q-rows
    const float4 v = wq[j];
    ushort4 h; h.x = f2h(v.x * s); h.y = f2h(v.y * s); h.z = f2h(v.z * s); h.w = f2h(v.w * s);
    w16[j] = h;
  } else {
    const int j = i - NX4 - NW4;
    if (j < NO4) {
      const float4 v = wo[j];
      ushort4 h; h.x = f2h(v.x); h.y = f2h(v.y); h.z = f2h(v.z); h.w = f2h(v.w);
      wo16[j] = h;
    }
  }
}

// ---------------------------------------------------------------- 64x128 f16 GEMM
// T4 counted-vmcnt pipeline: 3-deep LDS buffers, tile kt staged at iter kt-2,
// waited with s_waitcnt vmcnt(6) (per-wave 6 loads/tile; only the youngest tile's
// loads stay in flight) + RAW s_barrier — never vmcnt(0) in the main loop, so
// ~2 iterations of compute hide the (cold-L2) load latency. Stage is issued AFTER
// the barrier: all waves' ds_reads of the buffer being overwritten completed
// before their MFMA issue, which precedes barrier arrival. sched_barrier(0)
// fences both sides of the barrier so hipcc can't hoist ds_reads or the stage
// across it (rule #18). XOR chunk swizzle as before (pre-swizzled global source,
// swizzled ds_read, linear LDS dest). LDS 72 KiB -> 2 blocks/CU.
// Wave w computes 32x64: rows wm=(w>>1)*32, cols wn=(w&1)*64. acc[2][4].
// C[M][N] = A[M][K] * B[N][K]^T + bias. MODE 0: fp32 out. MODE 1: qkv epilogue ->
// k16[S][64] f16, vT[64][S] f16 (transposed!), q16[S][1024] f16 (bias x8 on q cols).
template<int MODE>
__global__ __launch_bounds__(256)
void gemm64(const ushort* __restrict__ A, const ushort* __restrict__ B,
            const float* __restrict__ bias, float* __restrict__ Cout,
            ushort* __restrict__ k16, ushort* __restrict__ vT, ushort* __restrict__ q16,
            int M, int N, int K) {
  __shared__ __align__(16) ushort sA[3][64 * 64];    // 3 x 8 KiB
  __shared__ __align__(16) ushort sB[3][128 * 64];   // 3 x 16 KiB  (total 72 KiB)
  const int t = threadIdx.x;
  const int w = t >> 6, lane = t & 63;
  const int quad = lane >> 4, l16 = lane & 15;
  const int wm = (w >> 1) * 32, wn = (w & 1) * 64;
  const int m0 = blockIdx.x * 64, n0 = blockIdx.y * 128;

  // staging: each async16 covers 8 rows x 64B; source chunk pre-swizzled by row&7.
  const int lr = lane >> 3;
  const int lc = (lane & 7) ^ lr;
  const size_t aBase = (size_t)(m0 + 16 * w + lr) * K + lc * 8;  // wave stages 16 A-rows
  const size_t bBase = (size_t)(n0 + 32 * w + lr) * K + lc * 8;  // wave stages 32 B-rows

  f32x4 acc[2][4] = {};

  // 6 async16 per wave per tile (2 A + 4 B)
  auto STAGE = [&](int ktile, int b) {
    const size_t koff = (size_t)ktile << 6;
#pragma unroll
    for (int i = 0; i < 2; ++i)
      async16(A + aBase + (size_t)(8 * i) * K + koff, &sA[b][(16 * w + 8 * i) * 64]);
#pragma unroll
    for (int i = 0; i < 4; ++i)
      async16(B + bBase + (size_t)(8 * i) * K + koff, &sB[b][(32 * w + 8 * i) * 64]);
  };

  const int NT = K >> 6;   // 16
  // prologue: stage tiles 0,1 (12 loads outstanding per wave)
  STAGE(0, 0);
  STAGE(1, 1);

  int c0 = 0, c1 = 1, c2 = 2;   // compute buf, next buf, stage target
  for (int kt = 0; kt < NT; ++kt) {
    // wait for tile kt's 6 loads (FIFO: only younger tile's 6 may remain)
    if (kt + 1 < NT) {
      asm volatile("s_waitcnt vmcnt(6)" ::: "memory");
    } else {
      asm volatile("s_waitcnt vmcnt(0)" ::: "memory");
    }
    __builtin_amdgcn_sched_barrier(0);
    __builtin_amdgcn_s_barrier();        // all waves' tile-kt loads landed;
    __builtin_amdgcn_sched_barrier(0);   // all waves done reading buf c2's old tile
    if (kt + 2 < NT) STAGE(kt + 2, c2);

    f16x8 af[2][2], bf[2][4];
#pragma unroll
    for (int kst = 0; kst < 2; ++kst) {
      const int cp = ((kst << 2) | quad) ^ (l16 & 7);   // row&7 == l16&7 (wm,16i ≡ 0 mod 8)
#pragma unroll
      for (int i = 0; i < 2; ++i)
        af[kst][i] = *(const f16x8*)(&sA[c0][(wm + 16 * i + l16) * 64 + cp * 8]);
#pragma unroll
      for (int j = 0; j < 4; ++j)
        bf[kst][j] = *(const f16x8*)(&sB[c0][(wn + 16 * j + l16) * 64 + cp * 8]);
    }
#pragma unroll
    for (int kst = 0; kst < 2; ++kst)
#pragma unroll
      for (int i = 0; i < 2; ++i)
#pragma unroll
        for (int j = 0; j < 4; ++j)
          acc[i][j] = __builtin_amdgcn_mfma_f32_16x16x32_f16(af[kst][i], bf[kst][j], acc[i][j], 0, 0, 0);

    const int tmp = c0; c0 = c1; c1 = c2; c2 = tmp;   // rotate buffers
  }

#pragma unroll
  for (int i = 0; i < 2; ++i)
#pragma unroll
    for (int j = 0; j < 4; ++j) {
      const int cb = n0 + wn + 16 * j;      // lane-uniform column base
      const int col = cb + l16;
      if (MODE == 0) {
        const float b = bias[col];
#pragma unroll
        for (int r = 0; r < 4; ++r) {
          const int row = m0 + wm + 16 * i + quad * 4 + r;
          Cout[(size_t)row * N + col] = acc[i][j][r] + b;
        }
      } else {
        const float bscale = (cb >= 2 * DHEAD) ? 8.0f : 1.0f;
        const float b = bias[col] * bscale;
#pragma unroll
        for (int r = 0; r < 4; ++r) {
          const int row = m0 + wm + 16 * i + quad * 4 + r;
          const ushort h = f2h(acc[i][j][r] + b);
          if (cb >= 2 * DHEAD) {
            q16[(size_t)row * DMODEL + (col - 2 * DHEAD)] = h;
          } else if (cb < DHEAD) {
            k16[(size_t)row * DHEAD + col] = h;
          } else {
            vT[(size_t)(col - DHEAD) * S_LEN + row] = h;
          }
        }
      }
    }
}

// ---------------------------------------------------------------- MFMA flash attention (f16)
// QT=4: one query per wave, grid 512 blocks, LDS 45 KiB -> 2 blocks/CU co-resident
// (latency overlap across blocks). Key window [jbase, jbase+160), jbase=(i0-127)&~7
// (clamped 0); max needed span 138 <= 160. Keys >= S_LEN read allocated slack and are
// masked (exp(-1e30)=0). LDS: Ksw[160][64] (chunk-swizzled, global_load_lds), aliased
// after QK^T by P[64][176]; Vt[64][176] staged from vT. All masking in softmax.
#define QT 4
#define KWIN 160
#define NTK 10
#define KST 5
#define PSTR 176

__global__ __launch_bounds__(256)
void attn_kernel(const ushort* __restrict__ k16, const ushort* __restrict__ vT,
                 const ushort* __restrict__ q16, ushort* __restrict__ obuf) {
  __shared__ __align__(16) ushort lds[64 * PSTR + 64 * PSTR];  // 45,056 B
  ushort* Ksw = lds;                  // [160][64] = 20,480 B (inside P region)
  ushort* P   = lds;                  // [64][176] = 22,528 B
  ushort* Vt  = lds + 64 * PSTR;      // [64][176] = 22,528 B

  const int t = threadIdx.x;
  const int i0 = blockIdx.x * QT;
  const int jbase = (i0 >= WIN - 1) ? ((i0 - (WIN - 1)) & ~7) : 0;
  const int w = t >> 6, lane = t & 63;
  const int quad = lane >> 4, l16 = lane & 15;
  const int qg = i0 + w;              // this wave's query

  // ---- stage K: 20 async 1KB instrs, XOR chunk swizzle (chunk c of row r at slot c^(r&7))
#pragma unroll
  for (int i = 0; i < 5; ++i) {
    const int n = 5 * w + i;                 // 0..19, 8 rows each
    const int r = 8 * n + (lane >> 3);
    const int cs = (lane & 7) ^ (r & 7);
    async16(k16 + (size_t)(jbase + r) * DHEAD + cs * 8, &Ksw[n * 512]);
  }
  // ---- stage Vt[64][160] from vT (16B aligned since jbase%8==0)
  {
    const int d = t >> 2, p = t & 3;
#pragma unroll
    for (int it = 0; it < 5; ++it) {
      const int c = p + 4 * it;              // 0..19
      const uint4 raw = *(const uint4*)(vT + (size_t)d * S_LEN + jbase + c * 8);
      *(uint4*)(&Vt[d * PSTR + c * 8]) = raw;
    }
  }
  // ---- Q fragments: lane m-row = head = l16
  f16x8 qf[2];
  {
    const size_t qbase = (size_t)qg * DMODEL + l16 * DHEAD;
#pragma unroll
    for (int kst = 0; kst < 2; ++kst)
      qf[kst] = *(const f16x8*)(q16 + qbase + kst * 32 + quad * 8);
  }
  __syncthreads();

  // ---- QK^T: acc[nt], rows=heads (quad*4+r), cols=keys (nt*16+l16)
  f32x4 acc[NTK] = {};
#pragma unroll
  for (int nt = 0; nt < NTK; ++nt) {
#pragma unroll
    for (int kst = 0; kst < 2; ++kst) {
      const int cp = ((kst << 2) | quad) ^ (l16 & 7);
      const f16x8 bf = *(const f16x8*)(&Ksw[(nt * 16 + l16) * 64 + cp * 8]);
      acc[nt] = __builtin_amdgcn_mfma_f32_16x16x32_f16(qf[kst], bf, acc[nt], 0, 0, 0);
    }
  }
  __syncthreads();  // K region dead; Vt stores drained

  // ---- mask + softmax (regs/shfl over 16 lanes), P -> LDS f16
  float inv_l[4];
#pragma unroll
  for (int nt = 0; nt < NTK; ++nt) {
    const int jg = jbase + nt * 16 + l16;
    const bool valid = (jg <= qg) && (jg > qg - WIN);
#pragma unroll
    for (int r = 0; r < 4; ++r)
      if (!valid) acc[nt][r] = -1e30f;
  }
#pragma unroll
  for (int r = 0; r < 4; ++r) {
    float m = acc[0][r];
#pragma unroll
    for (int nt = 1; nt < NTK; ++nt) m = fmaxf(m, acc[nt][r]);
#pragma unroll
    for (int off = 1; off < 16; off <<= 1) m = fmaxf(m, __shfl_xor(m, off));
    float s = 0.f;
#pragma unroll
    for (int nt = 0; nt < NTK; ++nt) {
      const float e = __expf(acc[nt][r] - m);
      acc[nt][r] = e;
      s += e;
    }
#pragma unroll
    for (int off = 1; off < 16; off <<= 1) s += __shfl_xor(s, off);
    inv_l[r] = 1.0f / s;
  }
  {
    const int mrow0 = w * 16 + quad * 4;
#pragma unroll
    for (int r = 0; r < 4; ++r)
#pragma unroll
      for (int nt = 0; nt < NTK; ++nt)
        P[(mrow0 + r) * PSTR + nt * 16 + l16] = f2h(acc[nt][r]);
  }
  __syncthreads();

  // ---- PV: o[nd], rows=heads, cols=d (nd*16+l16); 5 K-steps over 160 keys
  f32x4 o[4] = {};
#pragma unroll
  for (int kst = 0; kst < KST; ++kst) {
    const f16x8 a = *(const f16x8*)(&P[(w * 16 + l16) * PSTR + kst * 32 + quad * 8]);
#pragma unroll
    for (int nd = 0; nd < 4; ++nd) {
      const f16x8 b = *(const f16x8*)(&Vt[(nd * 16 + l16) * PSTR + kst * 32 + quad * 8]);
      o[nd] = __builtin_amdgcn_mfma_f32_16x16x32_f16(a, b, o[nd], 0, 0, 0);
    }
  }

  // ---- epilogue: normalize, write obuf f16
  {
    const size_t obase = (size_t)qg * DMODEL;
#pragma unroll
    for (int nd = 0; nd < 4; ++nd)
#pragma unroll
      for (int r = 0; r < 4; ++r) {
        const int col = (quad * 4 + r) * DHEAD + nd * 16 + l16;
        obuf[obase + col] = f2h(o[nd][r] * inv_l[r]);
      }
  }
}

// ---------------------------------------------------------------- launch
extern "C" void kernel_launch(void* const* d_in, const int* in_sizes, int n_in,
                              void* d_out, int out_size, void* d_ws, size_t ws_size,
                              hipStream_t stream) {
  const float* x    = (const float*)d_in[0];
  const float* Wqkv = (const float*)d_in[1];
  const float* bqkv = (const float*)d_in[2];
  const float* Wout = (const float*)d_in[3];
  const float* bout = (const float*)d_in[4];
  float* out = (float*)d_out;

  char* w = (char*)d_ws;
  ushort* x16  = (ushort*)(w + 0);          // 4,194,304 B
  ushort* w16  = (ushort*)(w + 4194304);    // 2,359,296 B
  ushort* wo16 = (ushort*)(w + 6553600);    // 2,097,152 B
  ushort* k16  = (ushort*)(w + 8650752);    // 270,336 B  (2112 rows x 64; rows >=2048 stay 0xAA)
  ushort* vT   = (ushort*)(w + 8921088);    // 270,336 B  (64 x 2048 + 8KB slack, stays 0xAA)
  ushort* q16  = (ushort*)(w + 9191424);    // 4,194,304 B
  ushort* obuf = (ushort*)(w + 13385728);   // 4,194,304 B   (total ~17.6 MB)

  convert_kernel<<<4224, 256, 0, stream>>>(
      (const float4*)x, (const float4*)Wqkv, (const float4*)Wout,
      (ushort4*)x16, (ushort4*)w16, (ushort4*)wo16);

  dim3 g1(S_LEN / 64, NQKV / 128);  // 32 x 9 = 288
  gemm64<1><<<g1, 256, 0, stream>>>(x16, w16, bqkv, nullptr, k16, vT, q16,
                                    S_LEN, NQKV, DMODEL);

  attn_kernel<<<S_LEN / QT, 256, 0, stream>>>(k16, vT, q16, obuf);  // 512 blocks

  dim3 g2(S_LEN / 64, DMODEL / 128);  // 32 x 8 = 256
  gemm64<0><<<g2, 256, 0, stream>>>(obuf, wo16, bout, out, nullptr, nullptr, nullptr,
                                    S_LEN, DMODEL, DMODEL);
}

// Round 5
// 108.236 us; speedup vs baseline: 1.0683x; 1.0683x over previous
//
#include <hip/hip_runtime.h>
#include <math.h>

#define S_LEN 2048
#define DMODEL 1024
#define NHEAD 16
#define DHEAD 64
#define WIN 128
#define NQKV 1152

typedef _Float16 f16x8 __attribute__((ext_vector_type(8)));
typedef float f32x4 __attribute__((ext_vector_type(4)));

__device__ __forceinline__ ushort f2h(float f) {
  union { _Float16 h; ushort u; } v; v.h = (_Float16)f; return v.u;
}

typedef __attribute__((address_space(1))) const unsigned GU;
typedef __attribute__((address_space(3))) unsigned LU;
__device__ __forceinline__ void async16(const ushort* g, ushort* l) {
  __builtin_amdgcn_global_load_lds((GU*)g, (LU*)l, 16, 0, 0);
}

// ---------------------------------------------------------------- convert fp32 -> f16
__global__ __launch_bounds__(256)
void convert_kernel(const float4* __restrict__ x, const float4* __restrict__ wq,
                    const float4* __restrict__ wo,
                    ushort4* __restrict__ x16, ushort4* __restrict__ w16,
                    ushort4* __restrict__ wo16) {
  const int NX4 = (S_LEN * DMODEL) / 4;       // 524288
  const int NW4 = (NQKV * DMODEL) / 4;        // 294912
  const int NO4 = (DMODEL * DMODEL) / 4;      // 262144
  const int i = blockIdx.x * 256 + threadIdx.x;
  if (i < NX4) {
    const float4 v = x[i];
    ushort4 h; h.x = f2h(v.x); h.y = f2h(v.y); h.z = f2h(v.z); h.w = f2h(v.w);
    x16[i] = h;
  } else if (i < NX4 + NW4) {
    const int j = i - NX4;
    const float s = ((j >> 8) >= 2 * DHEAD) ? 8.0f : 1.0f;  // fold sqrt(D) into q-rows
    const float4 v = wq[j];
    ushort4 h; h.x = f2h(v.x * s); h.y = f2h(v.y * s); h.z = f2h(v.z * s); h.w = f2h(v.w * s);
    w16[j] = h;
  } else {
    const int j = i - NX4 - NW4;
    if (j < NO4) {
      const float4 v = wo[j];
      ushort4 h; h.x = f2h(v.x); h.y = f2h(v.y); h.z = f2h(v.z); h.w = f2h(v.w);
      wo16[j] = h;
    }
  }
}

// ---------------------------------------------------------------- 64x64 f16 GEMM
// R3 schedule (known best: 2-deep dbuf, prefetch issued BEFORE compute, plain
// __syncthreads per K-tile), with tiles shrunk 64x128 -> 64x64 for TLP: LDS 32 KiB
// (5 blocks/CU capacity), grids 576/512 -> 2.25/2.0 blocks/CU resident. With fully
// cold caches (268 MB poison > L3) every staging load is a ~900cy HBM miss; the cure
// is co-resident blocks' overlapping misses, not deeper per-block pipelines (R4
// post-mortem: 3-deep counted-vmcnt + sched_barrier pinning lost occupancy, net +3.7us).
// XOR chunk swizzle as before: LDS dest linear (global_load_lds requirement), global
// source chunk pre-swizzled by (lane&7)^(row&7); ds_read applies the same involution;
// worst-case 2-way bank aliasing (free, m136).
// Wave w (2x2 layout) computes 32x32: rows wm=(w>>1)*32, cols wn=(w&1)*32. acc[2][2].
// C[M][N] = A[M][K] * B[N][K]^T + bias. MODE 0: fp32 out. MODE 1: qkv epilogue ->
// k16[S][64] f16, vT[64][S] f16 (transposed!), q16[S][1024] f16 (bias x8 on q cols).
template<int MODE>
__global__ __launch_bounds__(256)
void gemm64(const ushort* __restrict__ A, const ushort* __restrict__ B,
            const float* __restrict__ bias, float* __restrict__ Cout,
            ushort* __restrict__ k16, ushort* __restrict__ vT, ushort* __restrict__ q16,
            int M, int N, int K) {
  __shared__ __align__(16) ushort sA[2][64 * 64];    // 2 x 8 KiB
  __shared__ __align__(16) ushort sB[2][64 * 64];    // 2 x 8 KiB  (total 32 KiB)
  const int t = threadIdx.x;
  const int w = t >> 6, lane = t & 63;
  const int quad = lane >> 4, l16 = lane & 15;
  const int wm = (w >> 1) * 32, wn = (w & 1) * 32;
  const int m0 = blockIdx.x * 64, n0 = blockIdx.y * 64;

  // staging: each async16 covers 8 rows x 64B; source chunk pre-swizzled by row&7.
  // row&7 == lane>>3 for every staged row (16w+8i ≡ 0 mod 8).
  const int lr = lane >> 3;
  const int lc = (lane & 7) ^ lr;
  const size_t aBase = (size_t)(m0 + 16 * w + lr) * K + lc * 8;  // wave stages 16 A-rows
  const size_t bBase = (size_t)(n0 + 16 * w + lr) * K + lc * 8;  // wave stages 16 B-rows

  f32x4 acc[2][2] = {};

  // 4 async16 per wave per tile (2 A + 2 B)
  auto STAGE = [&](int ktile, int b) {
    const size_t koff = (size_t)ktile << 6;
#pragma unroll
    for (int i = 0; i < 2; ++i) {
      async16(A + aBase + (size_t)(8 * i) * K + koff, &sA[b][(16 * w + 8 * i) * 64]);
      async16(B + bBase + (size_t)(8 * i) * K + koff, &sB[b][(16 * w + 8 * i) * 64]);
    }
  };

  // prologue: stage K-tile 0 into buffer 0
  STAGE(0, 0);
  __syncthreads();

  const int NT = K >> 6;   // 16
  for (int kt = 0; kt < NT; ++kt) {
    const int cur = kt & 1;
    // issue next tile's loads FIRST — latency hides under this tile's compute
    if (kt + 1 < NT) STAGE(kt + 1, cur ^ 1);

    f16x8 af[2][2], bf[2][2];
#pragma unroll
    for (int kst = 0; kst < 2; ++kst) {
      const int cp = ((kst << 2) | quad) ^ (l16 & 7);   // row&7 == l16&7 (wm,16i ≡ 0 mod 8)
#pragma unroll
      for (int i = 0; i < 2; ++i) {
        af[kst][i] = *(const f16x8*)(&sA[cur][(wm + 16 * i + l16) * 64 + cp * 8]);
        bf[kst][i] = *(const f16x8*)(&sB[cur][(wn + 16 * i + l16) * 64 + cp * 8]);
      }
    }
#pragma unroll
    for (int kst = 0; kst < 2; ++kst)
#pragma unroll
      for (int i = 0; i < 2; ++i)
#pragma unroll
        for (int j = 0; j < 2; ++j)
          acc[i][j] = __builtin_amdgcn_mfma_f32_16x16x32_f16(af[kst][i], bf[kst][j], acc[i][j], 0, 0, 0);
    __syncthreads();   // drains prefetch (residual only) + protects buffer reuse
  }

#pragma unroll
  for (int i = 0; i < 2; ++i)
#pragma unroll
    for (int j = 0; j < 2; ++j) {
      const int cb = n0 + wn + 16 * j;      // lane-uniform column base
      const int col = cb + l16;
      if (MODE == 0) {
        const float b = bias[col];
#pragma unroll
        for (int r = 0; r < 4; ++r) {
          const int row = m0 + wm + 16 * i + quad * 4 + r;
          Cout[(size_t)row * N + col] = acc[i][j][r] + b;
        }
      } else {
        const float bscale = (cb >= 2 * DHEAD) ? 8.0f : 1.0f;
        const float b = bias[col] * bscale;
#pragma unroll
        for (int r = 0; r < 4; ++r) {
          const int row = m0 + wm + 16 * i + quad * 4 + r;
          const ushort h = f2h(acc[i][j][r] + b);
          if (cb >= 2 * DHEAD) {
            q16[(size_t)row * DMODEL + (col - 2 * DHEAD)] = h;
          } else if (cb < DHEAD) {
            k16[(size_t)row * DHEAD + col] = h;
          } else {
            vT[(size_t)(col - DHEAD) * S_LEN + row] = h;
          }
        }
      }
    }
}

// ---------------------------------------------------------------- MFMA flash attention (f16)
// QT=4: one query per wave, grid 512 blocks, LDS 45 KiB -> 2 blocks/CU co-resident
// (latency overlap across blocks). Key window [jbase, jbase+160), jbase=(i0-127)&~7
// (clamped 0); max needed span 138 <= 160. Keys >= S_LEN read allocated slack and are
// masked (exp(-1e30)=0). LDS: Ksw[160][64] (chunk-swizzled, global_load_lds), aliased
// after QK^T by P[64][176]; Vt[64][176] staged from vT. All masking in softmax.
#define QT 4
#define KWIN 160
#define NTK 10
#define KST 5
#define PSTR 176

__global__ __launch_bounds__(256)
void attn_kernel(const ushort* __restrict__ k16, const ushort* __restrict__ vT,
                 const ushort* __restrict__ q16, ushort* __restrict__ obuf) {
  __shared__ __align__(16) ushort lds[64 * PSTR + 64 * PSTR];  // 45,056 B
  ushort* Ksw = lds;                  // [160][64] = 20,480 B (inside P region)
  ushort* P   = lds;                  // [64][176] = 22,528 B
  ushort* Vt  = lds + 64 * PSTR;      // [64][176] = 22,528 B

  const int t = threadIdx.x;
  const int i0 = blockIdx.x * QT;
  const int jbase = (i0 >= WIN - 1) ? ((i0 - (WIN - 1)) & ~7) : 0;
  const int w = t >> 6, lane = t & 63;
  const int quad = lane >> 4, l16 = lane & 15;
  const int qg = i0 + w;              // this wave's query

  // ---- stage K: 20 async 1KB instrs, XOR chunk swizzle (chunk c of row r at slot c^(r&7))
#pragma unroll
  for (int i = 0; i < 5; ++i) {
    const int n = 5 * w + i;                 // 0..19, 8 rows each
    const int r = 8 * n + (lane >> 3);
    const int cs = (lane & 7) ^ (r & 7);
    async16(k16 + (size_t)(jbase + r) * DHEAD + cs * 8, &Ksw[n * 512]);
  }
  // ---- stage Vt[64][160] from vT (16B aligned since jbase%8==0)
  {
    const int d = t >> 2, p = t & 3;
#pragma unroll
    for (int it = 0; it < 5; ++it) {
      const int c = p + 4 * it;              // 0..19
      const uint4 raw = *(const uint4*)(vT + (size_t)d * S_LEN + jbase + c * 8);
      *(uint4*)(&Vt[d * PSTR + c * 8]) = raw;
    }
  }
  // ---- Q fragments: lane m-row = head = l16
  f16x8 qf[2];
  {
    const size_t qbase = (size_t)qg * DMODEL + l16 * DHEAD;
#pragma unroll
    for (int kst = 0; kst < 2; ++kst)
      qf[kst] = *(const f16x8*)(q16 + qbase + kst * 32 + quad * 8);
  }
  __syncthreads();

  // ---- QK^T: acc[nt], rows=heads (quad*4+r), cols=keys (nt*16+l16)
  f32x4 acc[NTK] = {};
#pragma unroll
  for (int nt = 0; nt < NTK; ++nt) {
#pragma unroll
    for (int kst = 0; kst < 2; ++kst) {
      const int cp = ((kst << 2) | quad) ^ (l16 & 7);
      const f16x8 bf = *(const f16x8*)(&Ksw[(nt * 16 + l16) * 64 + cp * 8]);
      acc[nt] = __builtin_amdgcn_mfma_f32_16x16x32_f16(qf[kst], bf, acc[nt], 0, 0, 0);
    }
  }
  __syncthreads();  // K region dead; Vt stores drained

  // ---- mask + softmax (regs/shfl over 16 lanes), P -> LDS f16
  float inv_l[4];
#pragma unroll
  for (int nt = 0; nt < NTK; ++nt) {
    const int jg = jbase + nt * 16 + l16;
    const bool valid = (jg <= qg) && (jg > qg - WIN);
#pragma unroll
    for (int r = 0; r < 4; ++r)
      if (!valid) acc[nt][r] = -1e30f;
  }
#pragma unroll
  for (int r = 0; r < 4; ++r) {
    float m = acc[0][r];
#pragma unroll
    for (int nt = 1; nt < NTK; ++nt) m = fmaxf(m, acc[nt][r]);
#pragma unroll
    for (int off = 1; off < 16; off <<= 1) m = fmaxf(m, __shfl_xor(m, off));
    float s = 0.f;
#pragma unroll
    for (int nt = 0; nt < NTK; ++nt) {
      const float e = __expf(acc[nt][r] - m);
      acc[nt][r] = e;
      s += e;
    }
#pragma unroll
    for (int off = 1; off < 16; off <<= 1) s += __shfl_xor(s, off);
    inv_l[r] = 1.0f / s;
  }
  {
    const int mrow0 = w * 16 + quad * 4;
#pragma unroll
    for (int r = 0; r < 4; ++r)
#pragma unroll
      for (int nt = 0; nt < NTK; ++nt)
        P[(mrow0 + r) * PSTR + nt * 16 + l16] = f2h(acc[nt][r]);
  }
  __syncthreads();

  // ---- PV: o[nd], rows=heads, cols=d (nd*16+l16); 5 K-steps over 160 keys
  f32x4 o[4] = {};
#pragma unroll
  for (int kst = 0; kst < KST; ++kst) {
    const f16x8 a = *(const f16x8*)(&P[(w * 16 + l16) * PSTR + kst * 32 + quad * 8]);
#pragma unroll
    for (int nd = 0; nd < 4; ++nd) {
      const f16x8 b = *(const f16x8*)(&Vt[(nd * 16 + l16) * PSTR + kst * 32 + quad * 8]);
      o[nd] = __builtin_amdgcn_mfma_f32_16x16x32_f16(a, b, o[nd], 0, 0, 0);
    }
  }

  // ---- epilogue: normalize, write obuf f16
  {
    const size_t obase = (size_t)qg * DMODEL;
#pragma unroll
    for (int nd = 0; nd < 4; ++nd)
#pragma unroll
      for (int r = 0; r < 4; ++r) {
        const int col = (quad * 4 + r) * DHEAD + nd * 16 + l16;
        obuf[obase + col] = f2h(o[nd][r] * inv_l[r]);
      }
  }
}

// ---------------------------------------------------------------- launch
extern "C" void kernel_launch(void* const* d_in, const int* in_sizes, int n_in,
                              void* d_out, int out_size, void* d_ws, size_t ws_size,
                              hipStream_t stream) {
  const float* x    = (const float*)d_in[0];
  const float* Wqkv = (const float*)d_in[1];
  const float* bqkv = (const float*)d_in[2];
  const float* Wout = (const float*)d_in[3];
  const float* bout = (const float*)d_in[4];
  float* out = (float*)d_out;

  char* w = (char*)d_ws;
  ushort* x16  = (ushort*)(w + 0);          // 4,194,304 B
  ushort* w16  = (ushort*)(w + 4194304);    // 2,359,296 B
  ushort* wo16 = (ushort*)(w + 6553600);    // 2,097,152 B
  ushort* k16  = (ushort*)(w + 8650752);    // 270,336 B  (2112 rows x 64; rows >=2048 stay 0xAA)
  ushort* vT   = (ushort*)(w + 8921088);    // 270,336 B  (64 x 2048 + 8KB slack, stays 0xAA)
  ushort* q16  = (ushort*)(w + 9191424);    // 4,194,304 B
  ushort* obuf = (ushort*)(w + 13385728);   // 4,194,304 B   (total ~17.6 MB)

  convert_kernel<<<4224, 256, 0, stream>>>(
      (const float4*)x, (const float4*)Wqkv, (const float4*)Wout,
      (ushort4*)x16, (ushort4*)w16, (ushort4*)wo16);

  dim3 g1(S_LEN / 64, NQKV / 64);  // 32 x 18 = 576
  gemm64<1><<<g1, 256, 0, stream>>>(x16, w16, bqkv, nullptr, k16, vT, q16,
                                    S_LEN, NQKV, DMODEL);

  attn_kernel<<<S_LEN / QT, 256, 0, stream>>>(k16, vT, q16, obuf);  // 512 blocks

  dim3 g2(S_LEN / 64, DMODEL / 64);  // 32 x 16 = 512
  gemm64<0><<<g2, 256, 0, stream>>>(obuf, wo16, bout, out, nullptr, nullptr, nullptr,
                                    S_LEN, DMODEL, DMODEL);
}